// Round 13
// baseline (126.279 us; speedup 1.0000x reference)
//
#include <hip/hip_runtime.h>
#include <cmath>

#define B_ 512
#define EPS_ 1e-8f

typedef __bf16 bf16x8 __attribute__((ext_vector_type(8)));
typedef float f32x4 __attribute__((ext_vector_type(4)));

__device__ __forceinline__ float sigmoidf_(float x) { return 1.f / (1.f + expf(-x)); }
__device__ __forceinline__ float softplusf_(float x) { return x > 20.f ? x : log1pf(expf(x)); }
__device__ __forceinline__ unsigned f2bf(float x) {
  union { float f; unsigned u; } v; v.f = x;
  unsigned r = v.u + 0x7FFF + ((v.u >> 16) & 1);
  return r >> 16;
}
__device__ __forceinline__ float bfhi2f(unsigned u) { return __uint_as_float(u & 0xffff0000u); }
__device__ __forceinline__ float bflo2f(unsigned u) { return __uint_as_float(u << 16); }
// packed f32->bf16 (RNE), lo = a, hi = b
__device__ __forceinline__ unsigned cvtpk(float a, float b) {
  unsigned r;
  asm("v_cvt_pk_bf16_f32 %0, %1, %2" : "=v"(r) : "v"(a), "v"(b));
  return r;
}
// raw v_rsq_f32 (~1e-6 rel)
__device__ __forceinline__ float rsq_(float x) {
  float r;
  asm("v_rsq_f32 %0, %1" : "=v"(r) : "v"(x));
  return r;
}

// ---------------- one prep kernel: x2b + all weight conversions (grid-stride)
__global__ void k_prep(const float* __restrict__ in_data, const float* __restrict__ prev_reads,
                       const float* __restrict__ h0,
                       const float* __restrict__ W_ih, const float* __restrict__ W_hh,
                       const float* __restrict__ b_ih, const float* __restrict__ b_hh,
                       const float* __restrict__ W_rh, const float* __restrict__ W_wh,
                       const float* __restrict__ W_out,
                       const float* __restrict__ b_rh, const float* __restrict__ b_wh,
                       unsigned short* __restrict__ x2b,
                       unsigned short* __restrict__ Wcatb, float* __restrict__ bcat,
                       unsigned short* __restrict__ W2b, unsigned short* __restrict__ Woutb,
                       float* __restrict__ bcat2) {
  const int stride = gridDim.x * blockDim.x;
  const int t0 = blockIdx.x * blockDim.x + threadIdx.x;
  for (int i = t0; i < 512 * 1024; i += stride) {
    const int b = i >> 10, j = i & 1023;
    float v;
    if (j < 256) v = in_data[(size_t)b * 256 + j];
    else if (j < 512) { const int jj = j - 256; v = prev_reads[(size_t)(jj >> 6) * B_ * 64 + (size_t)b * 64 + (jj & 63)]; }
    else v = h0[(size_t)b * 512 + (j - 512)];
    x2b[i] = (unsigned short)f2bf(v);
  }
  for (int i = t0; i < 2048 * 1024; i += stride) {
    const int j = i >> 10, k = i & 1023;
    Wcatb[i] = (unsigned short)f2bf(k < 512 ? W_ih[(size_t)j * 512 + k] : W_hh[(size_t)j * 512 + (k - 512)]);
  }
  for (int i = t0; i < 2048; i += stride) bcat[i] = b_ih[i] + b_hh[i];
  for (int i = t0; i < 143360; i += stride) W2b[i] = (unsigned short)f2bf(W_rh[i]);
  for (int i = t0; i < 405504; i += stride) W2b[143360 + i] = (unsigned short)f2bf(W_wh[i]);
  for (int i = t0; i < 196608; i += stride) Woutb[i] = (unsigned short)f2bf(W_out[i]);
  for (int i = t0; i < 280; i += stride) bcat2[i] = b_rh[i];
  for (int i = t0; i < 792; i += stride) bcat2[280 + i] = b_wh[i];
}

// ---------------- bf16 MFMA GEMM, one wave per 32x32 tile, direct-from-global frags
template <bool SIG>
__global__ __launch_bounds__(64) void k_gemm_mfma(const unsigned short* __restrict__ A, int lda,
                                                  const unsigned short* __restrict__ W,
                                                  const float* __restrict__ bias,
                                                  float* __restrict__ C,
                                                  int Nn, int Kk, int ldc) {
  const int l = threadIdx.x;
  const int m0 = blockIdx.y * 32, n0 = blockIdx.x * 32;
  const int lr = l & 15, lk = (l >> 4) * 8;
  f32x4 acc00 = {0.f, 0.f, 0.f, 0.f}, acc01 = acc00, acc10 = acc00, acc11 = acc00;
  const size_t pa0 = (size_t)(m0 + lr) * lda + lk;
  const size_t pa1 = pa0 + (size_t)16 * lda;
  const bool bok0 = (n0 + lr) < Nn, bok1 = (n0 + 16 + lr) < Nn;
  const size_t pb0 = (size_t)(n0 + lr) * Kk + lk;
  const size_t pb1 = pb0 + (size_t)16 * Kk;
#pragma unroll 4
  for (int k0 = 0; k0 < Kk; k0 += 32) {
    bf16x8 a0 = *(const bf16x8*)(A + pa0 + k0);
    bf16x8 a1 = *(const bf16x8*)(A + pa1 + k0);
    bf16x8 b0 = {}, b1 = {};
    if (bok0) b0 = *(const bf16x8*)(W + pb0 + k0);
    if (bok1) b1 = *(const bf16x8*)(W + pb1 + k0);
    acc00 = __builtin_amdgcn_mfma_f32_16x16x32_bf16(a0, b0, acc00, 0, 0, 0);
    acc01 = __builtin_amdgcn_mfma_f32_16x16x32_bf16(a0, b1, acc01, 0, 0, 0);
    acc10 = __builtin_amdgcn_mfma_f32_16x16x32_bf16(a1, b0, acc10, 0, 0, 0);
    acc11 = __builtin_amdgcn_mfma_f32_16x16x32_bf16(a1, b1, acc11, 0, 0, 0);
  }
  const int orow = (l >> 4) * 4;
  f32x4 accs[2][2] = {{acc00, acc01}, {acc10, acc11}};
#pragma unroll
  for (int mi = 0; mi < 2; ++mi) {
#pragma unroll
    for (int nj = 0; nj < 2; ++nj) {
      const int n = n0 + nj * 16 + lr;
      if (n < Nn) {
        const float bv = bias[n];
#pragma unroll
        for (int r = 0; r < 4; ++r) {
          const int m = m0 + mi * 16 + orow + r;
          float v = accs[mi][nj][r] + bv;
          if (SIG) v = 1.f / (1.f + expf(-v));
          C[(size_t)m * ldc + n] = v;
        }
      }
    }
  }
}

// ---------------- LSTM pointwise -> h (bf16) into Aoutb rows (stride 768)
__global__ void k_lstm(const float* __restrict__ gates, const float* __restrict__ c0,
                       unsigned short* __restrict__ Aoutb) {
  const int idx = blockIdx.x * blockDim.x + threadIdx.x;  // < 512*512
  const int b = idx >> 9, j = idx & 511;
  const float* g = gates + (size_t)b * 2048;
  const float ig = g[j], fg = g[512 + j], gg = g[1024 + j], og = g[1536 + j];
  const float c = sigmoidf_(fg) * c0[idx] + sigmoidf_(ig) * tanhf(gg);
  Aoutb[(size_t)b * 768 + j] = (unsigned short)f2bf(sigmoidf_(og) * tanhf(c));
}

// ---------------- fused NTM head loop: one 1024-thread block per batch row.
// LDS bf16 image (XOR-swizzled). r13 restructure: exp fused into the MFMA
// score pass (pe computed in-register from sacc + shuffled Gram diag), P2
// per-wave-rows (each wave computes wp for BOTH types of its own 64 rows ->
// sweep reads are self-written), read-normalization deferred to the store.
// 2 barriers per head (S2: Sw broadcast + WAR fence; S3: pe/redB/racc).
// NOTE (r7-r10): 1024-thread blocks are HARD-CAPPED at 64 VGPR; keep the
// image in LDS and live ranges tight (types processed sequentially in P2).
__global__ __launch_bounds__(1024, 4) void k_mega(const float* __restrict__ mem0,
                                                  const float* __restrict__ P,
                                                  const float* __restrict__ prev_w_r,
                                                  const float* __restrict__ prev_w_w,
                                                  unsigned short* __restrict__ Aoutb) {
  const int b = blockIdx.x;
  const int t = threadIdx.x;   // 1024
  const int l = t & 63;
  const int w = t >> 6;        // wave 0..15
  const int p = l & 15;
  const int q = l >> 4;        // 0..3

  __shared__ unsigned short smem[65536];                 // 1024x64 bf16 image (128 KB)
  __shared__ float Ar[1024], Aw[1024];                   // pe (unscaled exp) per type
  __shared__ float wpR[1024], wpW[1024];                 // unnormalized final weights
  __shared__ float racc[16][64];
  __shared__ unsigned short knbs[512];                   // 8 keys x 64 cols (bf16)
  __shared__ float parb[8][8];
  __shared__ unsigned ebp[4][32], abp[4][32];            // packed bf16 erase/add
  __shared__ float redBr[16], redBw[16], redCr[16], redCw[16];

  // ---- params phase (waves 0..7: unit = type*4+head)
  if (w < 8) {
    const int type = w >> 2, head = w & 3;
    const float* pp = P + (size_t)b * 1072 + (type == 0 ? head * 70 : 280 + head * 198);
    const float kv = tanhf(pp[l]);
    float ss = kv * kv;
#pragma unroll
    for (int off = 32; off > 0; off >>= 1) ss += __shfl_xor(ss, off);
    knbs[w * 64 + l] = (unsigned short)f2bf(kv * rsq_(fmaxf(ss, 1e-20f)));
    if (l == 0) {
      parb[w][0] = softplusf_(pp[64]);
      parb[w][1] = sigmoidf_(pp[65]);
      const float s0 = pp[66], s1 = pp[67], s2 = pp[68];
      const float mx = fmaxf(s0, fmaxf(s1, s2));
      const float e0 = expf(s0 - mx), e1 = expf(s1 - mx), e2 = expf(s2 - mx);
      const float inv = 1.f / (e0 + e1 + e2);
      parb[w][2] = e0 * inv; parb[w][3] = e1 * inv; parb[w][4] = e2 * inv;
      parb[w][5] = 1.f + softplusf_(pp[69]);
    }
    if (type == 1 && l < 32) {
      ebp[head][l] = cvtpk(sigmoidf_(pp[70 + 2 * l]), sigmoidf_(pp[70 + 2 * l + 1]));
      abp[head][l] = cvtpk(tanhf(pp[134 + 2 * l]), tanhf(pp[134 + 2 * l + 1]));
    }
  }

  // ---- staging: f32 memory -> bf16 LDS image (swizzled 16B chunks)
  {
    const float4* src = (const float4*)(mem0 + (size_t)b * 65536);
#pragma unroll 4
    for (int k = 0; k < 16; ++k) {
      const int v = k * 1024 + t;          // float4 index; n = v>>4, ch = v&15
      const float4 f = src[v];
      const int n = v >> 4, ch = v & 15;
      uint2 pk;
      pk.x = cvtpk(f.x, f.y);
      pk.y = cvtpk(f.z, f.w);
      *(uint2*)((char*)smem + n * 128 + (((ch >> 1) ^ (n & 7)) << 4) + ((ch & 1) << 3)) = pk;
    }
  }
  __syncthreads();  // S_a: image + params visible

  // ---- key B-fragments from LDS (cols 0..3 read keys, 4..7 write keys)
  bf16x8 kb0 = {}, kb1 = {};
  if (p < 8) {
    kb0 = *(const bf16x8*)&knbs[p * 64 + q * 8];
    kb1 = *(const bf16x8*)&knbs[p * 64 + 32 + q * 8];
  }

  // ---- fused MFMA score + exp pass over wave-owned rows (head hj, both types)
  // pe = exp(beta * score * rsq(nrm)) written to Ar/Aw; per-wave partial sums
  // to redBr/redBw.
  auto score_exp = [&](int hj) {
    const float br = parb[hj][0];
    const float bw = parb[4 + hj][0];
    const float bsel = (p == hj) ? br : bw;
    float accR = 0.f, accW = 0.f;
#pragma unroll
    for (int tt = 0; tt < 4; ++tt) {
      const int tile = w * 4 + tt;
      const int row = tile * 16 + p;
      const bf16x8 a0 = *(const bf16x8*)((char*)smem + row * 128 + ((q ^ (row & 7)) << 4));
      const bf16x8 a1 = *(const bf16x8*)((char*)smem + row * 128 + (((q + 4) ^ (row & 7)) << 4));
      f32x4 sacc = {0.f, 0.f, 0.f, 0.f}, gacc = {0.f, 0.f, 0.f, 0.f};
      sacc = __builtin_amdgcn_mfma_f32_16x16x32_bf16(a0, kb0, sacc, 0, 0, 0);
      sacc = __builtin_amdgcn_mfma_f32_16x16x32_bf16(a1, kb1, sacc, 0, 0, 0);
      gacc = __builtin_amdgcn_mfma_f32_16x16x32_bf16(a0, a0, gacc, 0, 0, 0);
      gacc = __builtin_amdgcn_mfma_f32_16x16x32_bf16(a1, a1, gacc, 0, 0, 0);
      // Gram diag nrm[q*4+r] lives at lane 20q+r (reg r) — shuffle to score lanes
      float nr4[4];
#pragma unroll
      for (int r = 0; r < 4; ++r) nr4[r] = __shfl(gacc[r], 20 * q + r);
      if (p == hj || p == 4 + hj) {
        f32x4 e4;
#pragma unroll
        for (int r = 0; r < 4; ++r)
          e4[r] = __expf(bsel * sacc[r] * rsq_(fmaxf(nr4[r], 1e-20f)));
        const float es = e4[0] + e4[1] + e4[2] + e4[3];
        if (p == hj) { *(f32x4*)&Ar[tile * 16 + q * 4] = e4; accR += es; }
        else         { *(f32x4*)&Aw[tile * 16 + q * 4] = e4; accW += es; }
      }
    }
    accR += __shfl_xor(accR, 16); accR += __shfl_xor(accR, 32);
    accW += __shfl_xor(accW, 16); accW += __shfl_xor(accW, 32);
    if (l == hj)     redBr[w] = accR;
    if (l == 4 + hj) redBw[w] = accW;
  };

  score_exp(0);
  __syncthreads();  // S_b: head-0 pe + partials visible

  const int u = w * 64 + l;  // row owned by this lane (P2 mapping)

  for (int i = 0; i < 4; ++i) {
    // ---- P2: per-wave rows, both types sequentially; wp -> self-owned slots
    {
      // read type
      float gsum = 0.f;
#pragma unroll
      for (int j = 0; j < 16; ++j) gsum += redBr[j];
      const float g = parb[i][1], sh0 = parb[i][2], sh1 = parb[i][3], sh2 = parb[i][4];
      const float gamma = parb[i][5];
      const float gi = g / gsum, gm = 1.f - g;
      const float* pw = prev_w_r + ((size_t)i * 512 + b) * 1024;
      const float wg = gi * Ar[u] + gm * pw[u];
      float wgm = __shfl_up(wg, 1);
      float wgp = __shfl_down(wg, 1);
      if (l == 0)  { const int um = (u + 1023) & 1023; wgm = gi * Ar[um] + gm * pw[um]; }
      if (l == 63) { const int up = (u + 1) & 1023;    wgp = gi * Ar[up] + gm * pw[up]; }
      const float ws = sh0 * wgm + sh1 * wg + sh2 * wgp;
      const float wp = (ws > 0.f) ? exp2f(gamma * __log2f(ws)) : 0.f;
      wpR[u] = wp;
      float s2 = wp;
#pragma unroll
      for (int off = 32; off > 0; off >>= 1) s2 += __shfl_xor(s2, off);
      if (l == 0) redCr[w] = s2;
    }
    if (i < 3) {
      // write type
      float gsum = 0.f;
#pragma unroll
      for (int j = 0; j < 16; ++j) gsum += redBw[j];
      const float g = parb[4 + i][1], sh0 = parb[4 + i][2], sh1 = parb[4 + i][3], sh2 = parb[4 + i][4];
      const float gamma = parb[4 + i][5];
      const float gi = g / gsum, gm = 1.f - g;
      const float* pw = prev_w_w + ((size_t)i * 512 + b) * 1024;
      const float wg = gi * Aw[u] + gm * pw[u];
      float wgm = __shfl_up(wg, 1);
      float wgp = __shfl_down(wg, 1);
      if (l == 0)  { const int um = (u + 1023) & 1023; wgm = gi * Aw[um] + gm * pw[um]; }
      if (l == 63) { const int up = (u + 1) & 1023;    wgp = gi * Aw[up] + gm * pw[up]; }
      const float ws = sh0 * wgm + sh1 * wg + sh2 * wgp;
      const float wp = (ws > 0.f) ? exp2f(gamma * __log2f(ws)) : 0.f;
      wpW[u] = wp;
      float s2 = wp;
#pragma unroll
      for (int off = 32; off > 0; off >>= 1) s2 += __shfl_xor(s2, off);
      if (l == 0) redCw[w] = s2;
    }
    __syncthreads();  // S2: Sw partials visible; fences Ar/Aw rewrite + racc reuse

    // ---- P3: sweep (raw wr, normalized ww) + fused next-head score/exp
    float inv2w = 0.f;
    if (i < 3) {
      float iw = 0.f;
#pragma unroll
      for (int j = 0; j < 16; ++j) iw += redCw[j];
      inv2w = 1.f / (iw + EPS_);
    }

    float e_0 = 0.f, e_1 = 0.f, e_2 = 0.f, e_3 = 0.f;
    float a_0 = 0.f, a_1 = 0.f, a_2 = 0.f, a_3 = 0.f;
    if (i < 3) {
      const unsigned ue0 = ebp[i][p * 2], ue1 = ebp[i][p * 2 + 1];
      const unsigned ua0 = abp[i][p * 2], ua1 = abp[i][p * 2 + 1];
      e_0 = bflo2f(ue0); e_1 = bfhi2f(ue0); e_2 = bflo2f(ue1); e_3 = bfhi2f(ue1);
      a_0 = bflo2f(ua0); a_1 = bfhi2f(ua0); a_2 = bflo2f(ua1); a_3 = bfhi2f(ua1);
    }

    char* const base0 = (char*)smem + (w * 64 + q) * 128 + ((((p >> 1) ^ q) << 4) | ((p & 1) << 3));
    char* const base1 = (char*)smem + (w * 64 + 4 + q) * 128 + ((((p >> 1) ^ (4 + q)) << 4) | ((p & 1) << 3));
    float r[4] = {0.f, 0.f, 0.f, 0.f};
#pragma unroll 2
    for (int it2 = 0; it2 < 8; ++it2) {
      {
        const int row = w * 64 + it2 * 8 + q;
        char* addr = base0 + it2 * 1024;
        uint2 pk = *(uint2*)addr;
        const float v0 = bflo2f(pk.x), v1 = bfhi2f(pk.x);
        const float v2 = bflo2f(pk.y), v3 = bfhi2f(pk.y);
        const float wr = wpR[row];
        r[0] = fmaf(wr, v0, r[0]); r[1] = fmaf(wr, v1, r[1]);
        r[2] = fmaf(wr, v2, r[2]); r[3] = fmaf(wr, v3, r[3]);
        if (i < 3) {
          const float ww = wpW[row] * inv2w;
          pk.x = cvtpk(fmaf(v0, fmaf(-ww, e_0, 1.f), ww * a_0),
                       fmaf(v1, fmaf(-ww, e_1, 1.f), ww * a_1));
          pk.y = cvtpk(fmaf(v2, fmaf(-ww, e_2, 1.f), ww * a_2),
                       fmaf(v3, fmaf(-ww, e_3, 1.f), ww * a_3));
          *(uint2*)addr = pk;
        }
      }
      {
        const int row = w * 64 + it2 * 8 + 4 + q;
        char* addr = base1 + it2 * 1024;
        uint2 pk = *(uint2*)addr;
        const float v0 = bflo2f(pk.x), v1 = bfhi2f(pk.x);
        const float v2 = bflo2f(pk.y), v3 = bfhi2f(pk.y);
        const float wr = wpR[row];
        r[0] = fmaf(wr, v0, r[0]); r[1] = fmaf(wr, v1, r[1]);
        r[2] = fmaf(wr, v2, r[2]); r[3] = fmaf(wr, v3, r[3]);
        if (i < 3) {
          const float ww = wpW[row] * inv2w;
          pk.x = cvtpk(fmaf(v0, fmaf(-ww, e_0, 1.f), ww * a_0),
                       fmaf(v1, fmaf(-ww, e_1, 1.f), ww * a_1));
          pk.y = cvtpk(fmaf(v2, fmaf(-ww, e_2, 1.f), ww * a_2),
                       fmaf(v3, fmaf(-ww, e_3, 1.f), ww * a_3));
          *(uint2*)addr = pk;
        }
      }
    }
    // fold read partials over the 4 q-groups (lane bits 4,5)
#pragma unroll
    for (int c = 0; c < 4; ++c) {
      r[c] += __shfl_xor(r[c], 16);
      r[c] += __shfl_xor(r[c], 32);
    }
    if (q == 0) *(f32x4*)&racc[w][p * 4] = *(f32x4*)r;

    if (i < 3) score_exp(i + 1);  // next head's pe + partials from updated image
    __syncthreads();              // S3: racc + pe + redB visible

    if (t < 64) {
      float ir = 0.f;
#pragma unroll
      for (int j = 0; j < 16; ++j) ir += redCr[j];
      const float inv2r = 1.f / (ir + EPS_);
      float s3 = 0.f;
#pragma unroll
      for (int wv = 0; wv < 16; ++wv) s3 += racc[wv][t];
      Aoutb[(size_t)b * 768 + 512 + i * 64 + t] = (unsigned short)f2bf(s3 * inv2r);
    }
  }
}

extern "C" void kernel_launch(void* const* d_in, const int* in_sizes, int n_in,
                              void* d_out, int out_size, void* d_ws, size_t ws_size,
                              hipStream_t stream) {
  (void)in_sizes; (void)n_in; (void)out_size; (void)ws_size;
  const float* in_data = (const float*)d_in[0];
  const float* memory = (const float*)d_in[1];
  const float* prev_reads = (const float*)d_in[2];
  const float* prev_w_r = (const float*)d_in[3];
  const float* prev_w_w = (const float*)d_in[4];
  const float* h0 = (const float*)d_in[5];
  const float* c0 = (const float*)d_in[6];
  const float* W_ih = (const float*)d_in[7];
  const float* b_ih = (const float*)d_in[8];
  const float* W_hh = (const float*)d_in[9];
  const float* b_hh = (const float*)d_in[10];
  const float* W_rh = (const float*)d_in[11];
  const float* b_rh = (const float*)d_in[12];
  const float* W_wh = (const float*)d_in[13];
  const float* b_wh = (const float*)d_in[14];
  const float* W_out = (const float*)d_in[15];
  const float* b_out = (const float*)d_in[16];
  float* out = (float*)d_out;

  char* base = (char*)d_ws;
  auto alloc = [&](size_t bytes) -> char* {
    char* p = base; base += (bytes + 255) & ~(size_t)255; return p;
  };
  unsigned short* x2b   = (unsigned short*)alloc((size_t)512 * 1024 * 2);
  unsigned short* Wcatb = (unsigned short*)alloc((size_t)2048 * 1024 * 2);
  float* bcat           = (float*)alloc(2048 * 4);
  float* gates          = (float*)alloc((size_t)512 * 2048 * 4);
  unsigned short* W2b   = (unsigned short*)alloc((size_t)1072 * 512 * 2);
  float* bcat2          = (float*)alloc(1072 * 4);
  unsigned short* Woutb = (unsigned short*)alloc((size_t)256 * 768 * 2);
  float* P              = (float*)alloc((size_t)512 * 1072 * 4);
  unsigned short* Aoutb = (unsigned short*)alloc((size_t)512 * 768 * 2);

  k_prep<<<2048, 256, 0, stream>>>(in_data, prev_reads, h0, W_ih, W_hh, b_ih, b_hh,
                                   W_rh, W_wh, W_out, b_rh, b_wh,
                                   x2b, Wcatb, bcat, W2b, Woutb, bcat2);
  k_gemm_mfma<false><<<dim3(64, 16), 64, 0, stream>>>(x2b, 1024, Wcatb, bcat, gates, 2048, 1024, 2048);
  k_lstm<<<1024, 256, 0, stream>>>(gates, c0, Aoutb);
  k_gemm_mfma<false><<<dim3(34, 16), 64, 0, stream>>>(Aoutb, 768, W2b, bcat2, P, 1072, 512, 1072);
  k_mega<<<512, 1024, 0, stream>>>(memory, P, prev_w_r, prev_w_w, Aoutb);
  k_gemm_mfma<true><<<dim3(8, 16), 64, 0, stream>>>(Aoutb, 768, Woutb, b_out, out, 256, 768, 256);
}

// Round 14
// 125.676 us; speedup vs baseline: 1.0048x; 1.0048x over previous
//
#include <hip/hip_runtime.h>
#include <cmath>

#define B_ 512
#define EPS_ 1e-8f

typedef __bf16 bf16x8 __attribute__((ext_vector_type(8)));
typedef float f32x4 __attribute__((ext_vector_type(4)));

__device__ __forceinline__ float sigmoidf_(float x) { return 1.f / (1.f + expf(-x)); }
__device__ __forceinline__ float softplusf_(float x) { return x > 20.f ? x : log1pf(expf(x)); }
__device__ __forceinline__ unsigned f2bf(float x) {
  union { float f; unsigned u; } v; v.f = x;
  unsigned r = v.u + 0x7FFF + ((v.u >> 16) & 1);
  return r >> 16;
}
__device__ __forceinline__ float bfhi2f(unsigned u) { return __uint_as_float(u & 0xffff0000u); }
__device__ __forceinline__ float bflo2f(unsigned u) { return __uint_as_float(u << 16); }
// packed f32->bf16 (RNE), lo = a, hi = b
__device__ __forceinline__ unsigned cvtpk(float a, float b) {
  unsigned r;
  asm("v_cvt_pk_bf16_f32 %0, %1, %2" : "=v"(r) : "v"(a), "v"(b));
  return r;
}
// raw v_rsq_f32 (~1e-6 rel)
__device__ __forceinline__ float rsq_(float x) {
  float r;
  asm("v_rsq_f32 %0, %1" : "=v"(r) : "v"(x));
  return r;
}

// ---------------- one prep kernel: x2b + all weight conversions (grid-stride)
__global__ void k_prep(const float* __restrict__ in_data, const float* __restrict__ prev_reads,
                       const float* __restrict__ h0,
                       const float* __restrict__ W_ih, const float* __restrict__ W_hh,
                       const float* __restrict__ b_ih, const float* __restrict__ b_hh,
                       const float* __restrict__ W_rh, const float* __restrict__ W_wh,
                       const float* __restrict__ W_out,
                       const float* __restrict__ b_rh, const float* __restrict__ b_wh,
                       unsigned short* __restrict__ x2b,
                       unsigned short* __restrict__ Wcatb, float* __restrict__ bcat,
                       unsigned short* __restrict__ W2b, unsigned short* __restrict__ Woutb,
                       float* __restrict__ bcat2) {
  const int stride = gridDim.x * blockDim.x;
  const int t0 = blockIdx.x * blockDim.x + threadIdx.x;
  for (int i = t0; i < 512 * 1024; i += stride) {
    const int b = i >> 10, j = i & 1023;
    float v;
    if (j < 256) v = in_data[(size_t)b * 256 + j];
    else if (j < 512) { const int jj = j - 256; v = prev_reads[(size_t)(jj >> 6) * B_ * 64 + (size_t)b * 64 + (jj & 63)]; }
    else v = h0[(size_t)b * 512 + (j - 512)];
    x2b[i] = (unsigned short)f2bf(v);
  }
  for (int i = t0; i < 2048 * 1024; i += stride) {
    const int j = i >> 10, k = i & 1023;
    Wcatb[i] = (unsigned short)f2bf(k < 512 ? W_ih[(size_t)j * 512 + k] : W_hh[(size_t)j * 512 + (k - 512)]);
  }
  for (int i = t0; i < 2048; i += stride) bcat[i] = b_ih[i] + b_hh[i];
  for (int i = t0; i < 143360; i += stride) W2b[i] = (unsigned short)f2bf(W_rh[i]);
  for (int i = t0; i < 405504; i += stride) W2b[143360 + i] = (unsigned short)f2bf(W_wh[i]);
  for (int i = t0; i < 196608; i += stride) Woutb[i] = (unsigned short)f2bf(W_out[i]);
  for (int i = t0; i < 280; i += stride) bcat2[i] = b_rh[i];
  for (int i = t0; i < 792; i += stride) bcat2[280 + i] = b_wh[i];
}

// ---------------- bf16 MFMA GEMM, one wave per 32x32 tile, direct-from-global frags
template <bool SIG>
__global__ __launch_bounds__(64) void k_gemm_mfma(const unsigned short* __restrict__ A, int lda,
                                                  const unsigned short* __restrict__ W,
                                                  const float* __restrict__ bias,
                                                  float* __restrict__ C,
                                                  int Nn, int Kk, int ldc) {
  const int l = threadIdx.x;
  const int m0 = blockIdx.y * 32, n0 = blockIdx.x * 32;
  const int lr = l & 15, lk = (l >> 4) * 8;
  f32x4 acc00 = {0.f, 0.f, 0.f, 0.f}, acc01 = acc00, acc10 = acc00, acc11 = acc00;
  const size_t pa0 = (size_t)(m0 + lr) * lda + lk;
  const size_t pa1 = pa0 + (size_t)16 * lda;
  const bool bok0 = (n0 + lr) < Nn, bok1 = (n0 + 16 + lr) < Nn;
  const size_t pb0 = (size_t)(n0 + lr) * Kk + lk;
  const size_t pb1 = pb0 + (size_t)16 * Kk;
#pragma unroll 4
  for (int k0 = 0; k0 < Kk; k0 += 32) {
    bf16x8 a0 = *(const bf16x8*)(A + pa0 + k0);
    bf16x8 a1 = *(const bf16x8*)(A + pa1 + k0);
    bf16x8 b0 = {}, b1 = {};
    if (bok0) b0 = *(const bf16x8*)(W + pb0 + k0);
    if (bok1) b1 = *(const bf16x8*)(W + pb1 + k0);
    acc00 = __builtin_amdgcn_mfma_f32_16x16x32_bf16(a0, b0, acc00, 0, 0, 0);
    acc01 = __builtin_amdgcn_mfma_f32_16x16x32_bf16(a0, b1, acc01, 0, 0, 0);
    acc10 = __builtin_amdgcn_mfma_f32_16x16x32_bf16(a1, b0, acc10, 0, 0, 0);
    acc11 = __builtin_amdgcn_mfma_f32_16x16x32_bf16(a1, b1, acc11, 0, 0, 0);
  }
  const int orow = (l >> 4) * 4;
  f32x4 accs[2][2] = {{acc00, acc01}, {acc10, acc11}};
#pragma unroll
  for (int mi = 0; mi < 2; ++mi) {
#pragma unroll
    for (int nj = 0; nj < 2; ++nj) {
      const int n = n0 + nj * 16 + lr;
      if (n < Nn) {
        const float bv = bias[n];
#pragma unroll
        for (int r = 0; r < 4; ++r) {
          const int m = m0 + mi * 16 + orow + r;
          float v = accs[mi][nj][r] + bv;
          if (SIG) v = 1.f / (1.f + expf(-v));
          C[(size_t)m * ldc + n] = v;
        }
      }
    }
  }
}

// ---------------- LSTM pointwise -> h (bf16) into Aoutb rows (stride 768)
__global__ void k_lstm(const float* __restrict__ gates, const float* __restrict__ c0,
                       unsigned short* __restrict__ Aoutb) {
  const int idx = blockIdx.x * blockDim.x + threadIdx.x;  // < 512*512
  const int b = idx >> 9, j = idx & 511;
  const float* g = gates + (size_t)b * 2048;
  const float ig = g[j], fg = g[512 + j], gg = g[1024 + j], og = g[1536 + j];
  const float c = sigmoidf_(fg) * c0[idx] + sigmoidf_(ig) * tanhf(gg);
  Aoutb[(size_t)b * 768 + j] = (unsigned short)f2bf(sigmoidf_(og) * tanhf(c));
}

// ---------------- fused NTM head loop: one 1024-thread block per batch row.
// LDS bf16 image (XOR-swizzled). r14 = r12 base (best measured: 101 us) with
// ONE change: wave-local staging (wave w stages rows [w*64,w*64+64), still
// fully coalesced) fused directly with score_pass(0) — same-wave LDS RAW is
// ordered by lgkmcnt, so the staging->score barrier disappears and the score
// MFMAs overlap staging latency per-wave. Params run first behind one cheap
// barrier. 3 barriers/head in the loop (r12 structure, proven).
// NOTE (r7-r10): 1024-thread blocks are HARD-CAPPED at 64 VGPR; keep image
// in LDS, live ranges tight.
__global__ __launch_bounds__(1024, 4) void k_mega(const float* __restrict__ mem0,
                                                  const float* __restrict__ P,
                                                  const float* __restrict__ prev_w_r,
                                                  const float* __restrict__ prev_w_w,
                                                  unsigned short* __restrict__ Aoutb) {
  const int b = blockIdx.x;
  const int t = threadIdx.x;   // 1024
  const int l = t & 63;
  const int w = t >> 6;        // wave 0..15
  const int p = l & 15;
  const int q = l >> 4;        // 0..3

  __shared__ unsigned short smem[65536];                 // 1024x64 bf16 image (128 KB)
  __shared__ float Ar[1024], Aw[1024];                   // scores -> pe
  __shared__ float nrm_s[1024];                          // Gram-diag norms
  __shared__ float wpR[1024], wpW[1024];                 // unnormalized final weights
  __shared__ float racc[16][64];
  __shared__ unsigned short knbs[512];                   // 8 keys x 64 cols (bf16)
  __shared__ float parb[8][8];
  __shared__ unsigned ebp[4][32], abp[4][32];            // packed bf16 erase/add
  __shared__ float pb[2][16][2];                         // prevw chunk-boundary values
  __shared__ float redB[16], redC[16];

  // ---- params phase (waves 0..7: unit = type*4+head)
  if (w < 8) {
    const int type = w >> 2, head = w & 3;
    const float* pp = P + (size_t)b * 1072 + (type == 0 ? head * 70 : 280 + head * 198);
    const float kv = tanhf(pp[l]);
    float ss = kv * kv;
#pragma unroll
    for (int off = 32; off > 0; off >>= 1) ss += __shfl_xor(ss, off);
    knbs[w * 64 + l] = (unsigned short)f2bf(kv * rsq_(fmaxf(ss, 1e-20f)));
    if (l == 0) {
      parb[w][0] = softplusf_(pp[64]);
      parb[w][1] = sigmoidf_(pp[65]);
      const float s0 = pp[66], s1 = pp[67], s2 = pp[68];
      const float mx = fmaxf(s0, fmaxf(s1, s2));
      const float e0 = expf(s0 - mx), e1 = expf(s1 - mx), e2 = expf(s2 - mx);
      const float inv = 1.f / (e0 + e1 + e2);
      parb[w][2] = e0 * inv; parb[w][3] = e1 * inv; parb[w][4] = e2 * inv;
      parb[w][5] = 1.f + softplusf_(pp[69]);
    }
    if (type == 1 && l < 32) {
      ebp[head][l] = cvtpk(sigmoidf_(pp[70 + 2 * l]), sigmoidf_(pp[70 + 2 * l + 1]));
      abp[head][l] = cvtpk(tanhf(pp[134 + 2 * l]), tanhf(pp[134 + 2 * l + 1]));
    }
  }
  __syncthreads();  // S_a: keys/params visible (cheap — params is ~0.2 us)

  // ---- key B-fragments from LDS (cols 0..3 read keys, 4..7 write keys)
  bf16x8 kb0 = {}, kb1 = {};
  if (p < 8) {
    kb0 = *(const bf16x8*)&knbs[p * 64 + q * 8];
    kb1 = *(const bf16x8*)&knbs[p * 64 + 32 + q * 8];
  }

  // ---- MFMA score pass over wave-owned rows: scores for head hj + Gram norms
  auto score_pass = [&](int hj) {
#pragma unroll
    for (int tt = 0; tt < 4; ++tt) {
      const int tile = w * 4 + tt;
      const int row = tile * 16 + p;
      const bf16x8 a0 = *(const bf16x8*)((char*)smem + row * 128 + (((q) ^ (row & 7)) << 4));
      const bf16x8 a1 = *(const bf16x8*)((char*)smem + row * 128 + (((q + 4) ^ (row & 7)) << 4));
      f32x4 sacc = {0.f, 0.f, 0.f, 0.f}, gacc = {0.f, 0.f, 0.f, 0.f};
      sacc = __builtin_amdgcn_mfma_f32_16x16x32_bf16(a0, kb0, sacc, 0, 0, 0);
      sacc = __builtin_amdgcn_mfma_f32_16x16x32_bf16(a1, kb1, sacc, 0, 0, 0);
      gacc = __builtin_amdgcn_mfma_f32_16x16x32_bf16(a0, a0, gacc, 0, 0, 0);
      gacc = __builtin_amdgcn_mfma_f32_16x16x32_bf16(a1, a1, gacc, 0, 0, 0);
      if (p == hj)       *(f32x4*)&Ar[tile * 16 + q * 4] = sacc;
      if (p == 4 + hj)   *(f32x4*)&Aw[tile * 16 + q * 4] = sacc;
      if ((p >> 2) == q) nrm_s[tile * 16 + p] = gacc[p & 3];
    }
  };

  // ---- wave-local staging: wave w stages rows [w*64, w*64+64) (coalesced:
  // lane l reads float4 index w*1024 + k*64 + l), then scores its own rows
  // immediately — no block barrier between staging and head-0 scores.
  {
    const float4* src = (const float4*)(mem0 + (size_t)b * 65536);
#pragma unroll 4
    for (int k = 0; k < 16; ++k) {
      const float4 f = src[w * 1024 + k * 64 + l];
      const int n = w * 64 + k * 4 + (l >> 4);
      const int ch = l & 15;
      uint2 pk;
      pk.x = cvtpk(f.x, f.y);
      pk.y = cvtpk(f.z, f.w);
      *(uint2*)((char*)smem + n * 128 + (((ch >> 1) ^ (n & 7)) << 4) + ((ch & 1) << 3)) = pk;
    }
  }
  score_pass(0);    // same-wave RAW on smem — ordered by lgkmcnt, no barrier
  __syncthreads();  // S_b: head-0 scores + norms visible block-wide

  const int h = t >> 9;      // 0: read half (waves 0-7), 1: write half (8-15)
  const int th = t & 511;
  const int w8 = (t & 511) >> 6;   // chunk index within half (0..7)
  float* Abuf = h ? Aw : Ar;
  float* Wbuf = h ? wpW : wpR;

  for (int i = 0; i < 4; ++i) {
    const float beta = parb[h * 4 + i][0], g = parb[h * 4 + i][1];
    const float sh0 = parb[h * 4 + i][2], sh1 = parb[h * 4 + i][3], sh2 = parb[h * 4 + i][4];
    const float gamma = parb[h * 4 + i][5];
    const float* prevw = (h ? prev_w_w : prev_w_r) + ((size_t)i * 512 + b) * 1024;

    // ---- P1: prevw -> regs (+ boundary table) + unscaled exp of scores
    const float pv0 = prevw[th];
    const float pv1 = prevw[th + 512];
    float e2_[2];
    float s = 0.f;
#pragma unroll
    for (int k = 0; k < 2; ++k) {
      const int u = th + 512 * k;
      const float z = beta * Abuf[u] * rsq_(fmaxf(nrm_s[u], 1e-20f));
      e2_[k] = __expf(z);
      s += e2_[k];
    }
    Abuf[th] = e2_[0];
    Abuf[th + 512] = e2_[1];
    if (l == 0)  { pb[h][w8][0] = pv0; pb[h][w8 + 8][0] = pv1; }
    if (l == 63) { pb[h][w8][1] = pv0; pb[h][w8 + 8][1] = pv1; }
#pragma unroll
    for (int off = 32; off > 0; off >>= 1) s += __shfl_xor(s, off);
    if (l == 0) redB[w] = s;
    __syncthreads();  // S1

    // ---- P2: gate + shift + sharpen; neighbors via shfl, boundaries via pb
    float gsum = 0.f;
#pragma unroll
    for (int j = 0; j < 8; ++j) gsum += redB[h * 8 + j];
    const float gi = g / gsum;
    const float gm = 1.f - g;
    float s2 = 0.f;
#pragma unroll
    for (int k = 0; k < 2; ++k) {
      const int u = th + 512 * k;
      const float wg0 = gi * Abuf[u] + gm * ((k == 0) ? pv0 : pv1);
      float wgm = __shfl_up(wg0, 1);
      float wgp = __shfl_down(wg0, 1);
      if (l == 0) {
        const int um = (u + 1023) & 1023;
        wgm = gi * Abuf[um] + gm * pb[h][um >> 6][1];
      }
      if (l == 63) {
        const int up = (u + 1) & 1023;
        wgp = gi * Abuf[up] + gm * pb[h][up >> 6][0];
      }
      const float ws = sh0 * wgm + sh1 * wg0 + sh2 * wgp;
      const float wp = (ws > 0.f) ? exp2f(gamma * __log2f(ws)) : 0.f;
      Wbuf[u] = wp;
      s2 += wp;
    }
#pragma unroll
    for (int off = 32; off > 0; off >>= 1) s2 += __shfl_xor(s2, off);
    if (l == 0) redC[w] = s2;
    __syncthreads();  // S2

    // ---- P3: sweep wave-owned rows (reads + in-place update, read-side norm)
    float ir = 0.f, iw = 0.f;
#pragma unroll
    for (int j = 0; j < 8; ++j) { ir += redC[j]; iw += redC[8 + j]; }
    const float inv2r = 1.f / (ir + EPS_);
    const float inv2w = 1.f / (iw + EPS_);

    float e_0 = 0.f, e_1 = 0.f, e_2 = 0.f, e_3 = 0.f;
    float a_0 = 0.f, a_1 = 0.f, a_2 = 0.f, a_3 = 0.f;
    if (i < 3) {
      const unsigned ue0 = ebp[i][p * 2], ue1 = ebp[i][p * 2 + 1];
      const unsigned ua0 = abp[i][p * 2], ua1 = abp[i][p * 2 + 1];
      e_0 = bflo2f(ue0); e_1 = bfhi2f(ue0); e_2 = bflo2f(ue1); e_3 = bfhi2f(ue1);
      a_0 = bflo2f(ua0); a_1 = bfhi2f(ua0); a_2 = bflo2f(ua1); a_3 = bfhi2f(ua1);
    }

    // two hoisted swizzled base pointers: rows w*64+{q, 4+q} (+8 per step)
    char* const base0 = (char*)smem + (w * 64 + q) * 128 + ((((p >> 1) ^ q) << 4) | ((p & 1) << 3));
    char* const base1 = (char*)smem + (w * 64 + 4 + q) * 128 + ((((p >> 1) ^ (4 + q)) << 4) | ((p & 1) << 3));
    float r[4] = {0.f, 0.f, 0.f, 0.f};
#pragma unroll 2
    for (int it2 = 0; it2 < 8; ++it2) {
      {
        const int row = w * 64 + it2 * 8 + q;
        char* addr = base0 + it2 * 1024;
        uint2 pk = *(uint2*)addr;
        const float v0 = bflo2f(pk.x), v1 = bfhi2f(pk.x);
        const float v2 = bflo2f(pk.y), v3 = bfhi2f(pk.y);
        const float wr = wpR[row] * inv2r;
        r[0] = fmaf(wr, v0, r[0]); r[1] = fmaf(wr, v1, r[1]);
        r[2] = fmaf(wr, v2, r[2]); r[3] = fmaf(wr, v3, r[3]);
        if (i < 3) {
          const float ww = wpW[row] * inv2w;
          pk.x = cvtpk(fmaf(v0, fmaf(-ww, e_0, 1.f), ww * a_0),
                       fmaf(v1, fmaf(-ww, e_1, 1.f), ww * a_1));
          pk.y = cvtpk(fmaf(v2, fmaf(-ww, e_2, 1.f), ww * a_2),
                       fmaf(v3, fmaf(-ww, e_3, 1.f), ww * a_3));
          *(uint2*)addr = pk;
        }
      }
      {
        const int row = w * 64 + it2 * 8 + 4 + q;
        char* addr = base1 + it2 * 1024;
        uint2 pk = *(uint2*)addr;
        const float v0 = bflo2f(pk.x), v1 = bfhi2f(pk.x);
        const float v2 = bflo2f(pk.y), v3 = bfhi2f(pk.y);
        const float wr = wpR[row] * inv2r;
        r[0] = fmaf(wr, v0, r[0]); r[1] = fmaf(wr, v1, r[1]);
        r[2] = fmaf(wr, v2, r[2]); r[3] = fmaf(wr, v3, r[3]);
        if (i < 3) {
          const float ww = wpW[row] * inv2w;
          pk.x = cvtpk(fmaf(v0, fmaf(-ww, e_0, 1.f), ww * a_0),
                       fmaf(v1, fmaf(-ww, e_1, 1.f), ww * a_1));
          pk.y = cvtpk(fmaf(v2, fmaf(-ww, e_2, 1.f), ww * a_2),
                       fmaf(v3, fmaf(-ww, e_3, 1.f), ww * a_3));
          *(uint2*)addr = pk;
        }
      }
    }
    // fold read partials over the 4 q-groups (lane bits 4,5)
#pragma unroll
    for (int c = 0; c < 4; ++c) {
      r[c] += __shfl_xor(r[c], 16);
      r[c] += __shfl_xor(r[c], 32);
    }
    if (q == 0) *(f32x4*)&racc[w][p * 4] = *(f32x4*)r;

    if (i < 3) score_pass(i + 1);  // own-row scores/norms from updated image
    __syncthreads();               // S3

    if (t < 64) {
      float s3 = 0.f;
#pragma unroll
      for (int wv = 0; wv < 16; ++wv) s3 += racc[wv][t];
      Aoutb[(size_t)b * 768 + 512 + i * 64 + t] = (unsigned short)f2bf(s3);
    }
  }
}

extern "C" void kernel_launch(void* const* d_in, const int* in_sizes, int n_in,
                              void* d_out, int out_size, void* d_ws, size_t ws_size,
                              hipStream_t stream) {
  (void)in_sizes; (void)n_in; (void)out_size; (void)ws_size;
  const float* in_data = (const float*)d_in[0];
  const float* memory = (const float*)d_in[1];
  const float* prev_reads = (const float*)d_in[2];
  const float* prev_w_r = (const float*)d_in[3];
  const float* prev_w_w = (const float*)d_in[4];
  const float* h0 = (const float*)d_in[5];
  const float* c0 = (const float*)d_in[6];
  const float* W_ih = (const float*)d_in[7];
  const float* b_ih = (const float*)d_in[8];
  const float* W_hh = (const float*)d_in[9];
  const float* b_hh = (const float*)d_in[10];
  const float* W_rh = (const float*)d_in[11];
  const float* b_rh = (const float*)d_in[12];
  const float* W_wh = (const float*)d_in[13];
  const float* b_wh = (const float*)d_in[14];
  const float* W_out = (const float*)d_in[15];
  const float* b_out = (const float*)d_in[16];
  float* out = (float*)d_out;

  char* base = (char*)d_ws;
  auto alloc = [&](size_t bytes) -> char* {
    char* p = base; base += (bytes + 255) & ~(size_t)255; return p;
  };
  unsigned short* x2b   = (unsigned short*)alloc((size_t)512 * 1024 * 2);
  unsigned short* Wcatb = (unsigned short*)alloc((size_t)2048 * 1024 * 2);
  float* bcat           = (float*)alloc(2048 * 4);
  float* gates          = (float*)alloc((size_t)512 * 2048 * 4);
  unsigned short* W2b   = (unsigned short*)alloc((size_t)1072 * 512 * 2);
  float* bcat2          = (float*)alloc(1072 * 4);
  unsigned short* Woutb = (unsigned short*)alloc((size_t)256 * 768 * 2);
  float* P              = (float*)alloc((size_t)512 * 1072 * 4);
  unsigned short* Aoutb = (unsigned short*)alloc((size_t)512 * 768 * 2);

  k_prep<<<2048, 256, 0, stream>>>(in_data, prev_reads, h0, W_ih, W_hh, b_ih, b_hh,
                                   W_rh, W_wh, W_out, b_rh, b_wh,
                                   x2b, Wcatb, bcat, W2b, Woutb, bcat2);
  k_gemm_mfma<false><<<dim3(64, 16), 64, 0, stream>>>(x2b, 1024, Wcatb, bcat, gates, 2048, 1024, 2048);
  k_lstm<<<1024, 256, 0, stream>>>(gates, c0, Aoutb);
  k_gemm_mfma<false><<<dim3(34, 16), 64, 0, stream>>>(Aoutb, 768, W2b, bcat2, P, 1072, 512, 1072);
  k_mega<<<512, 1024, 0, stream>>>(memory, P, prev_w_r, prev_w_w, Aoutb);
  k_gemm_mfma<true><<<dim3(8, 16), 64, 0, stream>>>(Aoutb, 768, Woutb, b_out, out, 256, 768, 256);
}

// Round 15
// 124.548 us; speedup vs baseline: 1.0139x; 1.0091x over previous
//
#include <hip/hip_runtime.h>
#include <cmath>

#define B_ 512
#define EPS_ 1e-8f

typedef __bf16 bf16x8 __attribute__((ext_vector_type(8)));
typedef float f32x4 __attribute__((ext_vector_type(4)));

__device__ __forceinline__ float sigmoidf_(float x) { return 1.f / (1.f + expf(-x)); }
__device__ __forceinline__ float softplusf_(float x) { return x > 20.f ? x : log1pf(expf(x)); }
__device__ __forceinline__ unsigned f2bf(float x) {
  union { float f; unsigned u; } v; v.f = x;
  unsigned r = v.u + 0x7FFF + ((v.u >> 16) & 1);
  return r >> 16;
}
__device__ __forceinline__ float bfhi2f(unsigned u) { return __uint_as_float(u & 0xffff0000u); }
__device__ __forceinline__ float bflo2f(unsigned u) { return __uint_as_float(u << 16); }
// packed f32->bf16 (RNE), lo = a, hi = b
__device__ __forceinline__ unsigned cvtpk(float a, float b) {
  unsigned r;
  asm("v_cvt_pk_bf16_f32 %0, %1, %2" : "=v"(r) : "v"(a), "v"(b));
  return r;
}
// raw v_rsq_f32 (~1e-6 rel)
__device__ __forceinline__ float rsq_(float x) {
  float r;
  asm("v_rsq_f32 %0, %1" : "=v"(r) : "v"(x));
  return r;
}

// ---------------- one prep kernel: x2b + all weight conversions (grid-stride)
__global__ void k_prep(const float* __restrict__ in_data, const float* __restrict__ prev_reads,
                       const float* __restrict__ h0,
                       const float* __restrict__ W_ih, const float* __restrict__ W_hh,
                       const float* __restrict__ b_ih, const float* __restrict__ b_hh,
                       const float* __restrict__ W_rh, const float* __restrict__ W_wh,
                       const float* __restrict__ W_out,
                       const float* __restrict__ b_rh, const float* __restrict__ b_wh,
                       unsigned short* __restrict__ x2b,
                       unsigned short* __restrict__ Wcatb, float* __restrict__ bcat,
                       unsigned short* __restrict__ W2b, unsigned short* __restrict__ Woutb,
                       float* __restrict__ bcat2) {
  const int stride = gridDim.x * blockDim.x;
  const int t0 = blockIdx.x * blockDim.x + threadIdx.x;
  for (int i = t0; i < 512 * 1024; i += stride) {
    const int b = i >> 10, j = i & 1023;
    float v;
    if (j < 256) v = in_data[(size_t)b * 256 + j];
    else if (j < 512) { const int jj = j - 256; v = prev_reads[(size_t)(jj >> 6) * B_ * 64 + (size_t)b * 64 + (jj & 63)]; }
    else v = h0[(size_t)b * 512 + (j - 512)];
    x2b[i] = (unsigned short)f2bf(v);
  }
  for (int i = t0; i < 2048 * 1024; i += stride) {
    const int j = i >> 10, k = i & 1023;
    Wcatb[i] = (unsigned short)f2bf(k < 512 ? W_ih[(size_t)j * 512 + k] : W_hh[(size_t)j * 512 + (k - 512)]);
  }
  for (int i = t0; i < 2048; i += stride) bcat[i] = b_ih[i] + b_hh[i];
  for (int i = t0; i < 143360; i += stride) W2b[i] = (unsigned short)f2bf(W_rh[i]);
  for (int i = t0; i < 405504; i += stride) W2b[143360 + i] = (unsigned short)f2bf(W_wh[i]);
  for (int i = t0; i < 196608; i += stride) Woutb[i] = (unsigned short)f2bf(W_out[i]);
  for (int i = t0; i < 280; i += stride) bcat2[i] = b_rh[i];
  for (int i = t0; i < 792; i += stride) bcat2[280 + i] = b_wh[i];
}

// ---------------- bf16 MFMA GEMM, one wave per 32x32 tile, direct-from-global frags
template <bool SIG>
__global__ __launch_bounds__(64) void k_gemm_mfma(const unsigned short* __restrict__ A, int lda,
                                                  const unsigned short* __restrict__ W,
                                                  const float* __restrict__ bias,
                                                  float* __restrict__ C,
                                                  int Nn, int Kk, int ldc) {
  const int l = threadIdx.x;
  const int m0 = blockIdx.y * 32, n0 = blockIdx.x * 32;
  const int lr = l & 15, lk = (l >> 4) * 8;
  f32x4 acc00 = {0.f, 0.f, 0.f, 0.f}, acc01 = acc00, acc10 = acc00, acc11 = acc00;
  const size_t pa0 = (size_t)(m0 + lr) * lda + lk;
  const size_t pa1 = pa0 + (size_t)16 * lda;
  const bool bok0 = (n0 + lr) < Nn, bok1 = (n0 + 16 + lr) < Nn;
  const size_t pb0 = (size_t)(n0 + lr) * Kk + lk;
  const size_t pb1 = pb0 + (size_t)16 * Kk;
#pragma unroll 4
  for (int k0 = 0; k0 < Kk; k0 += 32) {
    bf16x8 a0 = *(const bf16x8*)(A + pa0 + k0);
    bf16x8 a1 = *(const bf16x8*)(A + pa1 + k0);
    bf16x8 b0 = {}, b1 = {};
    if (bok0) b0 = *(const bf16x8*)(W + pb0 + k0);
    if (bok1) b1 = *(const bf16x8*)(W + pb1 + k0);
    acc00 = __builtin_amdgcn_mfma_f32_16x16x32_bf16(a0, b0, acc00, 0, 0, 0);
    acc01 = __builtin_amdgcn_mfma_f32_16x16x32_bf16(a0, b1, acc01, 0, 0, 0);
    acc10 = __builtin_amdgcn_mfma_f32_16x16x32_bf16(a1, b0, acc10, 0, 0, 0);
    acc11 = __builtin_amdgcn_mfma_f32_16x16x32_bf16(a1, b1, acc11, 0, 0, 0);
  }
  const int orow = (l >> 4) * 4;
  f32x4 accs[2][2] = {{acc00, acc01}, {acc10, acc11}};
#pragma unroll
  for (int mi = 0; mi < 2; ++mi) {
#pragma unroll
    for (int nj = 0; nj < 2; ++nj) {
      const int n = n0 + nj * 16 + lr;
      if (n < Nn) {
        const float bv = bias[n];
#pragma unroll
        for (int r = 0; r < 4; ++r) {
          const int m = m0 + mi * 16 + orow + r;
          float v = accs[mi][nj][r] + bv;
          if (SIG) v = 1.f / (1.f + expf(-v));
          C[(size_t)m * ldc + n] = v;
        }
      }
    }
  }
}

// ---------------- LSTM pointwise -> h (bf16) into Aoutb rows (stride 768)
__global__ void k_lstm(const float* __restrict__ gates, const float* __restrict__ c0,
                       unsigned short* __restrict__ Aoutb) {
  const int idx = blockIdx.x * blockDim.x + threadIdx.x;  // < 512*512
  const int b = idx >> 9, j = idx & 511;
  const float* g = gates + (size_t)b * 2048;
  const float ig = g[j], fg = g[512 + j], gg = g[1024 + j], og = g[1536 + j];
  const float c = sigmoidf_(fg) * c0[idx] + sigmoidf_(ig) * tanhf(gg);
  Aoutb[(size_t)b * 768 + j] = (unsigned short)f2bf(sigmoidf_(og) * tanhf(c));
}

// ---------------- fused NTM head loop: one 1024-thread block per batch row.
// r15 = r12 base (best measured: 101 us k_mega) with ONE structural change:
// the exp phase is wave-local (wave w exps its OWN score rows [64w,64w+64)
// for BOTH key types right after its own score_pass — same-wave LDS RAW,
// no shuffle broadcasts, lane-consecutive rows) and prevw(i+1) loads issue
// in the same phase, held in regs across the barrier. Barriers: 14 -> 10
// (2 per head: {P2 | S2 | sweep+scores+exp+prevw | S3}).
// NOTE (r7-r10): 1024-thread blocks are HARD-CAPPED at 64 VGPR; keep image
// in LDS, live ranges tight. r14's wave-local STAGING regressed (load->use
// serialization) — staging stays block-wide.
__global__ __launch_bounds__(1024, 4) void k_mega(const float* __restrict__ mem0,
                                                  const float* __restrict__ P,
                                                  const float* __restrict__ prev_w_r,
                                                  const float* __restrict__ prev_w_w,
                                                  unsigned short* __restrict__ Aoutb) {
  const int b = blockIdx.x;
  const int t = threadIdx.x;   // 1024
  const int l = t & 63;
  const int w = t >> 6;        // wave 0..15
  const int p = l & 15;
  const int q = l >> 4;        // 0..3

  __shared__ unsigned short smem[65536];                 // 1024x64 bf16 image (128 KB)
  __shared__ float Ar[1024], Aw[1024];                   // raw scores -> pe
  __shared__ float nrm_s[1024];                          // Gram-diag norms
  __shared__ float wpR[1024], wpW[1024];                 // unnormalized final weights
  __shared__ float racc[16][64];
  __shared__ unsigned short knbs[512];                   // 8 keys x 64 cols (bf16)
  __shared__ float parb[8][8];
  __shared__ unsigned ebp[4][32], abp[4][32];            // packed bf16 erase/add
  __shared__ float pb[2][16][2];                         // prevw chunk-boundary values
  __shared__ float redBr[16], redBw[16], redC[16];

  // ---- params phase (waves 0..7: unit = type*4+head)
  if (w < 8) {
    const int type = w >> 2, head = w & 3;
    const float* pp = P + (size_t)b * 1072 + (type == 0 ? head * 70 : 280 + head * 198);
    const float kv = tanhf(pp[l]);
    float ss = kv * kv;
#pragma unroll
    for (int off = 32; off > 0; off >>= 1) ss += __shfl_xor(ss, off);
    knbs[w * 64 + l] = (unsigned short)f2bf(kv * rsq_(fmaxf(ss, 1e-20f)));
    if (l == 0) {
      parb[w][0] = softplusf_(pp[64]);
      parb[w][1] = sigmoidf_(pp[65]);
      const float s0 = pp[66], s1 = pp[67], s2 = pp[68];
      const float mx = fmaxf(s0, fmaxf(s1, s2));
      const float e0 = expf(s0 - mx), e1 = expf(s1 - mx), e2 = expf(s2 - mx);
      const float inv = 1.f / (e0 + e1 + e2);
      parb[w][2] = e0 * inv; parb[w][3] = e1 * inv; parb[w][4] = e2 * inv;
      parb[w][5] = 1.f + softplusf_(pp[69]);
    }
    if (type == 1 && l < 32) {
      ebp[head][l] = cvtpk(sigmoidf_(pp[70 + 2 * l]), sigmoidf_(pp[70 + 2 * l + 1]));
      abp[head][l] = cvtpk(tanhf(pp[134 + 2 * l]), tanhf(pp[134 + 2 * l + 1]));
    }
  }

  // ---- staging: f32 memory -> bf16 LDS image (swizzled 16B chunks, block-wide)
  {
    const float4* src = (const float4*)(mem0 + (size_t)b * 65536);
#pragma unroll 4
    for (int k = 0; k < 16; ++k) {
      const int v = k * 1024 + t;          // float4 index; n = v>>4, ch = v&15
      const float4 f = src[v];
      const int n = v >> 4, ch = v & 15;
      uint2 pk;
      pk.x = cvtpk(f.x, f.y);
      pk.y = cvtpk(f.z, f.w);
      *(uint2*)((char*)smem + n * 128 + (((ch >> 1) ^ (n & 7)) << 4) + ((ch & 1) << 3)) = pk;
    }
  }
  __syncthreads();  // S_a: image + params visible

  // ---- key B-fragments from LDS (cols 0..3 read keys, 4..7 write keys)
  bf16x8 kb0 = {}, kb1 = {};
  if (p < 8) {
    kb0 = *(const bf16x8*)&knbs[p * 64 + q * 8];
    kb1 = *(const bf16x8*)&knbs[p * 64 + 32 + q * 8];
  }

  // ---- MFMA score pass over wave-owned rows: raw scores + Gram norms
  auto score_pass = [&](int hj) {
#pragma unroll
    for (int tt = 0; tt < 4; ++tt) {
      const int tile = w * 4 + tt;
      const int row = tile * 16 + p;
      const bf16x8 a0 = *(const bf16x8*)((char*)smem + row * 128 + (((q) ^ (row & 7)) << 4));
      const bf16x8 a1 = *(const bf16x8*)((char*)smem + row * 128 + (((q + 4) ^ (row & 7)) << 4));
      f32x4 sacc = {0.f, 0.f, 0.f, 0.f}, gacc = {0.f, 0.f, 0.f, 0.f};
      sacc = __builtin_amdgcn_mfma_f32_16x16x32_bf16(a0, kb0, sacc, 0, 0, 0);
      sacc = __builtin_amdgcn_mfma_f32_16x16x32_bf16(a1, kb1, sacc, 0, 0, 0);
      gacc = __builtin_amdgcn_mfma_f32_16x16x32_bf16(a0, a0, gacc, 0, 0, 0);
      gacc = __builtin_amdgcn_mfma_f32_16x16x32_bf16(a1, a1, gacc, 0, 0, 0);
      if (p == hj)       *(f32x4*)&Ar[tile * 16 + q * 4] = sacc;
      if (p == 4 + hj)   *(f32x4*)&Aw[tile * 16 + q * 4] = sacc;
      if ((p >> 2) == q) nrm_s[tile * 16 + p] = gacc[p & 3];
    }
  };

  // ---- wave-local exp: wave w exps its own rows [64w,64w+64) for BOTH types
  auto do_exp = [&](int hj) {
    const int row = w * 64 + l;
    const float rn = rsq_(fmaxf(nrm_s[row], 1e-20f));
    const float per = __expf(parb[hj][0] * Ar[row] * rn);
    const float pew = __expf(parb[4 + hj][0] * Aw[row] * rn);
    Ar[row] = per;
    Aw[row] = pew;
    float sr = per, sw = pew;
#pragma unroll
    for (int off = 32; off > 0; off >>= 1) {
      sr += __shfl_xor(sr, off);
      sw += __shfl_xor(sw, off);
    }
    if (l == 0) { redBr[w] = sr; redBw[w] = sw; }
  };

  const int h = t >> 9;      // 0: read half (waves 0-7), 1: write half (8-15)
  const int th = t & 511;
  const int w8 = th >> 6;    // chunk index within half (0..7)
  float* Abuf = h ? Aw : Ar;
  float* Wbuf = h ? wpW : wpR;

  float pv0, pv1;
  auto load_pw = [&](int ii) {
    const float* pw = (h ? prev_w_w : prev_w_r) + ((size_t)ii * 512 + b) * 1024;
    pv0 = pw[th];
    pv1 = pw[th + 512];
    if (l == 0)  { pb[h][w8][0] = pv0; pb[h][w8 + 8][0] = pv1; }
    if (l == 63) { pb[h][w8][1] = pv0; pb[h][w8 + 8][1] = pv1; }
  };

  score_pass(0);
  do_exp(0);
  load_pw(0);
  __syncthreads();  // S_b: head-0 pe + redB + pb visible

  for (int i = 0; i < 4; ++i) {
    // ---- Phase B: Aout store for head i-1, then P2 for head i
    if (i > 0 && t < 64) {
      float s3 = 0.f;
#pragma unroll
      for (int wv = 0; wv < 16; ++wv) s3 += racc[wv][t];
      Aoutb[(size_t)b * 768 + 512 + (i - 1) * 64 + t] = (unsigned short)f2bf(s3);
    }
    const float g = parb[h * 4 + i][1];
    const float sh0 = parb[h * 4 + i][2], sh1 = parb[h * 4 + i][3], sh2 = parb[h * 4 + i][4];
    const float gamma = parb[h * 4 + i][5];
    float gsum = 0.f;
    {
      const float* rb = h ? redBw : redBr;
#pragma unroll
      for (int j = 0; j < 16; ++j) gsum += rb[j];
    }
    const float gi = g / gsum;
    const float gm = 1.f - g;
    float s2 = 0.f;
#pragma unroll
    for (int k = 0; k < 2; ++k) {
      const int u = th + 512 * k;
      const float wg0 = gi * Abuf[u] + gm * ((k == 0) ? pv0 : pv1);
      float wgm = __shfl_up(wg0, 1);
      float wgp = __shfl_down(wg0, 1);
      if (l == 0) {
        const int um = (u + 1023) & 1023;
        wgm = gi * Abuf[um] + gm * pb[h][um >> 6][1];
      }
      if (l == 63) {
        const int up = (u + 1) & 1023;
        wgp = gi * Abuf[up] + gm * pb[h][up >> 6][0];
      }
      const float ws = sh0 * wgm + sh1 * wg0 + sh2 * wgp;
      const float wp = (ws > 0.f) ? exp2f(gamma * __log2f(ws)) : 0.f;
      Wbuf[u] = wp;
      s2 += wp;
    }
#pragma unroll
    for (int off = 32; off > 0; off >>= 1) s2 += __shfl_xor(s2, off);
    if (l == 0) redC[w] = s2;
    __syncthreads();  // S2: wp + redC visible; pe arrays free for rewrite

    // ---- Phase A: sweep head i (read-accum + update) + next-head prep
    float ir = 0.f, iw = 0.f;
#pragma unroll
    for (int j = 0; j < 8; ++j) { ir += redC[j]; iw += redC[8 + j]; }
    const float inv2r = 1.f / (ir + EPS_);
    const float inv2w = 1.f / (iw + EPS_);

    float e_0 = 0.f, e_1 = 0.f, e_2 = 0.f, e_3 = 0.f;
    float a_0 = 0.f, a_1 = 0.f, a_2 = 0.f, a_3 = 0.f;
    if (i < 3) {
      const unsigned ue0 = ebp[i][p * 2], ue1 = ebp[i][p * 2 + 1];
      const unsigned ua0 = abp[i][p * 2], ua1 = abp[i][p * 2 + 1];
      e_0 = bflo2f(ue0); e_1 = bfhi2f(ue0); e_2 = bflo2f(ue1); e_3 = bfhi2f(ue1);
      a_0 = bflo2f(ua0); a_1 = bfhi2f(ua0); a_2 = bflo2f(ua1); a_3 = bfhi2f(ua1);
    }

    // two hoisted swizzled base pointers: rows w*64+{q, 4+q} (+8 per step)
    char* const base0 = (char*)smem + (w * 64 + q) * 128 + ((((p >> 1) ^ q) << 4) | ((p & 1) << 3));
    char* const base1 = (char*)smem + (w * 64 + 4 + q) * 128 + ((((p >> 1) ^ (4 + q)) << 4) | ((p & 1) << 3));
    float r[4] = {0.f, 0.f, 0.f, 0.f};
#pragma unroll 2
    for (int it2 = 0; it2 < 8; ++it2) {
      {
        const int row = w * 64 + it2 * 8 + q;
        char* addr = base0 + it2 * 1024;
        uint2 pk = *(uint2*)addr;
        const float v0 = bflo2f(pk.x), v1 = bfhi2f(pk.x);
        const float v2 = bflo2f(pk.y), v3 = bfhi2f(pk.y);
        const float wr = wpR[row] * inv2r;
        r[0] = fmaf(wr, v0, r[0]); r[1] = fmaf(wr, v1, r[1]);
        r[2] = fmaf(wr, v2, r[2]); r[3] = fmaf(wr, v3, r[3]);
        if (i < 3) {
          const float ww = wpW[row] * inv2w;
          pk.x = cvtpk(fmaf(v0, fmaf(-ww, e_0, 1.f), ww * a_0),
                       fmaf(v1, fmaf(-ww, e_1, 1.f), ww * a_1));
          pk.y = cvtpk(fmaf(v2, fmaf(-ww, e_2, 1.f), ww * a_2),
                       fmaf(v3, fmaf(-ww, e_3, 1.f), ww * a_3));
          *(uint2*)addr = pk;
        }
      }
      {
        const int row = w * 64 + it2 * 8 + 4 + q;
        char* addr = base1 + it2 * 1024;
        uint2 pk = *(uint2*)addr;
        const float v0 = bflo2f(pk.x), v1 = bfhi2f(pk.x);
        const float v2 = bflo2f(pk.y), v3 = bfhi2f(pk.y);
        const float wr = wpR[row] * inv2r;
        r[0] = fmaf(wr, v0, r[0]); r[1] = fmaf(wr, v1, r[1]);
        r[2] = fmaf(wr, v2, r[2]); r[3] = fmaf(wr, v3, r[3]);
        if (i < 3) {
          const float ww = wpW[row] * inv2w;
          pk.x = cvtpk(fmaf(v0, fmaf(-ww, e_0, 1.f), ww * a_0),
                       fmaf(v1, fmaf(-ww, e_1, 1.f), ww * a_1));
          pk.y = cvtpk(fmaf(v2, fmaf(-ww, e_2, 1.f), ww * a_2),
                       fmaf(v3, fmaf(-ww, e_3, 1.f), ww * a_3));
          *(uint2*)addr = pk;
        }
      }
    }
    // fold read partials over the 4 q-groups (lane bits 4,5)
#pragma unroll
    for (int c = 0; c < 4; ++c) {
      r[c] += __shfl_xor(r[c], 16);
      r[c] += __shfl_xor(r[c], 32);
    }
    if (q == 0) *(f32x4*)&racc[w][p * 4] = *(f32x4*)r;

    if (i < 3) {
      score_pass(i + 1);  // own-row raw scores/norms from updated image
      do_exp(i + 1);      // own-row pe + redB partials (same-wave, no barrier)
      load_pw(i + 1);     // prevw for next head -> regs + pb boundaries
    }
    __syncthreads();      // S3: racc + pe + redB + pb visible
  }

  if (t < 64) {
    float s3 = 0.f;
#pragma unroll
    for (int wv = 0; wv < 16; ++wv) s3 += racc[wv][t];
    Aoutb[(size_t)b * 768 + 512 + 3 * 64 + t] = (unsigned short)f2bf(s3);
  }
}

extern "C" void kernel_launch(void* const* d_in, const int* in_sizes, int n_in,
                              void* d_out, int out_size, void* d_ws, size_t ws_size,
                              hipStream_t stream) {
  (void)in_sizes; (void)n_in; (void)out_size; (void)ws_size;
  const float* in_data = (const float*)d_in[0];
  const float* memory = (const float*)d_in[1];
  const float* prev_reads = (const float*)d_in[2];
  const float* prev_w_r = (const float*)d_in[3];
  const float* prev_w_w = (const float*)d_in[4];
  const float* h0 = (const float*)d_in[5];
  const float* c0 = (const float*)d_in[6];
  const float* W_ih = (const float*)d_in[7];
  const float* b_ih = (const float*)d_in[8];
  const float* W_hh = (const float*)d_in[9];
  const float* b_hh = (const float*)d_in[10];
  const float* W_rh = (const float*)d_in[11];
  const float* b_rh = (const float*)d_in[12];
  const float* W_wh = (const float*)d_in[13];
  const float* b_wh = (const float*)d_in[14];
  const float* W_out = (const float*)d_in[15];
  const float* b_out = (const float*)d_in[16];
  float* out = (float*)d_out;

  char* base = (char*)d_ws;
  auto alloc = [&](size_t bytes) -> char* {
    char* p = base; base += (bytes + 255) & ~(size_t)255; return p;
  };
  unsigned short* x2b   = (unsigned short*)alloc((size_t)512 * 1024 * 2);
  unsigned short* Wcatb = (unsigned short*)alloc((size_t)2048 * 1024 * 2);
  float* bcat           = (float*)alloc(2048 * 4);
  float* gates          = (float*)alloc((size_t)512 * 2048 * 4);
  unsigned short* W2b   = (unsigned short*)alloc((size_t)1072 * 512 * 2);
  float* bcat2          = (float*)alloc(1072 * 4);
  unsigned short* Woutb = (unsigned short*)alloc((size_t)256 * 768 * 2);
  float* P              = (float*)alloc((size_t)512 * 1072 * 4);
  unsigned short* Aoutb = (unsigned short*)alloc((size_t)512 * 768 * 2);

  k_prep<<<2048, 256, 0, stream>>>(in_data, prev_reads, h0, W_ih, W_hh, b_ih, b_hh,
                                   W_rh, W_wh, W_out, b_rh, b_wh,
                                   x2b, Wcatb, bcat, W2b, Woutb, bcat2);
  k_gemm_mfma<false><<<dim3(64, 16), 64, 0, stream>>>(x2b, 1024, Wcatb, bcat, gates, 2048, 1024, 2048);
  k_lstm<<<1024, 256, 0, stream>>>(gates, c0, Aoutb);
  k_gemm_mfma<false><<<dim3(34, 16), 64, 0, stream>>>(Aoutb, 768, W2b, bcat2, P, 1072, 512, 1072);
  k_mega<<<512, 1024, 0, stream>>>(memory, P, prev_w_r, prev_w_w, Aoutb);
  k_gemm_mfma<true><<<dim3(8, 16), 64, 0, stream>>>(Aoutb, 768, Woutb, b_out, out, 256, 768, 256);
}

// Round 16
// 120.834 us; speedup vs baseline: 1.0451x; 1.0307x over previous
//
#include <hip/hip_runtime.h>
#include <cmath>

#define B_ 512
#define EPS_ 1e-8f

typedef __bf16 bf16x8 __attribute__((ext_vector_type(8)));
typedef float f32x4 __attribute__((ext_vector_type(4)));

__device__ __forceinline__ float sigmoidf_(float x) { return 1.f / (1.f + expf(-x)); }
__device__ __forceinline__ float softplusf_(float x) { return x > 20.f ? x : log1pf(expf(x)); }
__device__ __forceinline__ unsigned f2bf(float x) {
  union { float f; unsigned u; } v; v.f = x;
  unsigned r = v.u + 0x7FFF + ((v.u >> 16) & 1);
  return r >> 16;
}
__device__ __forceinline__ float bfhi2f(unsigned u) { return __uint_as_float(u & 0xffff0000u); }
__device__ __forceinline__ float bflo2f(unsigned u) { return __uint_as_float(u << 16); }
// packed f32->bf16 (RNE), lo = a, hi = b
__device__ __forceinline__ unsigned cvtpk(float a, float b) {
  unsigned r;
  asm("v_cvt_pk_bf16_f32 %0, %1, %2" : "=v"(r) : "v"(a), "v"(b));
  return r;
}
// raw v_rsq_f32 (~1e-6 rel) — replaces sqrtf+fdiv on score paths
__device__ __forceinline__ float rsq_(float x) {
  float r;
  asm("v_rsq_f32 %0, %1" : "=v"(r) : "v"(x));
  return r;
}

// ---------------- one prep kernel: x2b + all weight conversions (grid-stride)
__global__ void k_prep(const float* __restrict__ in_data, const float* __restrict__ prev_reads,
                       const float* __restrict__ h0,
                       const float* __restrict__ W_ih, const float* __restrict__ W_hh,
                       const float* __restrict__ b_ih, const float* __restrict__ b_hh,
                       const float* __restrict__ W_rh, const float* __restrict__ W_wh,
                       const float* __restrict__ W_out,
                       const float* __restrict__ b_rh, const float* __restrict__ b_wh,
                       unsigned short* __restrict__ x2b,
                       unsigned short* __restrict__ Wcatb, float* __restrict__ bcat,
                       unsigned short* __restrict__ W2b, unsigned short* __restrict__ Woutb,
                       float* __restrict__ bcat2) {
  const int stride = gridDim.x * blockDim.x;
  const int t0 = blockIdx.x * blockDim.x + threadIdx.x;
  for (int i = t0; i < 512 * 1024; i += stride) {
    const int b = i >> 10, j = i & 1023;
    float v;
    if (j < 256) v = in_data[(size_t)b * 256 + j];
    else if (j < 512) { const int jj = j - 256; v = prev_reads[(size_t)(jj >> 6) * B_ * 64 + (size_t)b * 64 + (jj & 63)]; }
    else v = h0[(size_t)b * 512 + (j - 512)];
    x2b[i] = (unsigned short)f2bf(v);
  }
  for (int i = t0; i < 2048 * 1024; i += stride) {
    const int j = i >> 10, k = i & 1023;
    Wcatb[i] = (unsigned short)f2bf(k < 512 ? W_ih[(size_t)j * 512 + k] : W_hh[(size_t)j * 512 + (k - 512)]);
  }
  for (int i = t0; i < 2048; i += stride) bcat[i] = b_ih[i] + b_hh[i];
  for (int i = t0; i < 143360; i += stride) W2b[i] = (unsigned short)f2bf(W_rh[i]);
  for (int i = t0; i < 405504; i += stride) W2b[143360 + i] = (unsigned short)f2bf(W_wh[i]);
  for (int i = t0; i < 196608; i += stride) Woutb[i] = (unsigned short)f2bf(W_out[i]);
  for (int i = t0; i < 280; i += stride) bcat2[i] = b_rh[i];
  for (int i = t0; i < 792; i += stride) bcat2[280 + i] = b_wh[i];
}

// ---------------- bf16 MFMA GEMM, one wave per 32x32 tile, direct-from-global frags
template <bool SIG>
__global__ __launch_bounds__(64) void k_gemm_mfma(const unsigned short* __restrict__ A, int lda,
                                                  const unsigned short* __restrict__ W,
                                                  const float* __restrict__ bias,
                                                  float* __restrict__ C,
                                                  int Nn, int Kk, int ldc) {
  const int l = threadIdx.x;
  const int m0 = blockIdx.y * 32, n0 = blockIdx.x * 32;
  const int lr = l & 15, lk = (l >> 4) * 8;
  f32x4 acc00 = {0.f, 0.f, 0.f, 0.f}, acc01 = acc00, acc10 = acc00, acc11 = acc00;
  const size_t pa0 = (size_t)(m0 + lr) * lda + lk;
  const size_t pa1 = pa0 + (size_t)16 * lda;
  const bool bok0 = (n0 + lr) < Nn, bok1 = (n0 + 16 + lr) < Nn;
  const size_t pb0 = (size_t)(n0 + lr) * Kk + lk;
  const size_t pb1 = pb0 + (size_t)16 * Kk;
#pragma unroll 4
  for (int k0 = 0; k0 < Kk; k0 += 32) {
    bf16x8 a0 = *(const bf16x8*)(A + pa0 + k0);
    bf16x8 a1 = *(const bf16x8*)(A + pa1 + k0);
    bf16x8 b0 = {}, b1 = {};
    if (bok0) b0 = *(const bf16x8*)(W + pb0 + k0);
    if (bok1) b1 = *(const bf16x8*)(W + pb1 + k0);
    acc00 = __builtin_amdgcn_mfma_f32_16x16x32_bf16(a0, b0, acc00, 0, 0, 0);
    acc01 = __builtin_amdgcn_mfma_f32_16x16x32_bf16(a0, b1, acc01, 0, 0, 0);
    acc10 = __builtin_amdgcn_mfma_f32_16x16x32_bf16(a1, b0, acc10, 0, 0, 0);
    acc11 = __builtin_amdgcn_mfma_f32_16x16x32_bf16(a1, b1, acc11, 0, 0, 0);
  }
  const int orow = (l >> 4) * 4;
  f32x4 accs[2][2] = {{acc00, acc01}, {acc10, acc11}};
#pragma unroll
  for (int mi = 0; mi < 2; ++mi) {
#pragma unroll
    for (int nj = 0; nj < 2; ++nj) {
      const int n = n0 + nj * 16 + lr;
      if (n < Nn) {
        const float bv = bias[n];
#pragma unroll
        for (int r = 0; r < 4; ++r) {
          const int m = m0 + mi * 16 + orow + r;
          float v = accs[mi][nj][r] + bv;
          if (SIG) v = 1.f / (1.f + expf(-v));
          C[(size_t)m * ldc + n] = v;
        }
      }
    }
  }
}

// ---------------- LSTM pointwise -> h (bf16) into Aoutb rows (stride 768)
__global__ void k_lstm(const float* __restrict__ gates, const float* __restrict__ c0,
                       unsigned short* __restrict__ Aoutb) {
  const int idx = blockIdx.x * blockDim.x + threadIdx.x;  // < 512*512
  const int b = idx >> 9, j = idx & 511;
  const float* g = gates + (size_t)b * 2048;
  const float ig = g[j], fg = g[512 + j], gg = g[1024 + j], og = g[1536 + j];
  const float c = sigmoidf_(fg) * c0[idx] + sigmoidf_(ig) * tanhf(gg);
  Aoutb[(size_t)b * 768 + j] = (unsigned short)f2bf(sigmoidf_(og) * tanhf(c));
}

// ---------------- fused NTM head loop: one 1024-thread block per batch row.
// LDS bf16 memory image (XOR-swizzled 16B chunks), MFMA scores + Gram norms.
// 3 barriers/head: P1 (prevw->regs + unscaled exp), P2 (gate/shift/sharpen,
// neighbors via shfl + boundary table pb), P3 (sweep + next-head score_pass).
// This is the r12 configuration — empirical optimum over 5 schedule variants
// (r13 fused-exp/shfl-bcast: +6.5us; r14 wave-local staging: +6us; r15
// wave-local exp 2-barrier: +3.5us). k_mega is latency-bound at 1 blk/CU;
// chain length is conserved under rearrangement.
// NOTE (r7-r10): 1024-thread blocks are HARD-CAPPED at 64 VGPR regardless of
// launch_bounds 2nd arg; register-resident memory images spill (1 GB scratch).
// Keep the image in LDS (~60 VGPR used).
__global__ __launch_bounds__(1024, 4) void k_mega(const float* __restrict__ mem0,
                                                  const float* __restrict__ P,
                                                  const float* __restrict__ prev_w_r,
                                                  const float* __restrict__ prev_w_w,
                                                  unsigned short* __restrict__ Aoutb) {
  const int b = blockIdx.x;
  const int t = threadIdx.x;   // 1024
  const int l = t & 63;
  const int w = t >> 6;        // wave 0..15
  const int p = l & 15;
  const int q = l >> 4;        // 0..3

  __shared__ unsigned short smem[65536];                 // 1024x64 bf16 image (128 KB)
  __shared__ float Ar[1024], Aw[1024];                   // scores -> pe
  __shared__ float nrm_s[1024];                          // Gram-diag norms
  __shared__ float wpR[1024], wpW[1024];                 // unnormalized final weights
  __shared__ float racc[16][64];
  __shared__ unsigned short knbs[512];                   // 8 keys x 64 cols (bf16)
  __shared__ float parb[8][8];
  __shared__ unsigned ebp[4][32], abp[4][32];            // packed bf16 erase/add
  __shared__ float pb[2][16][2];                         // prevw chunk-boundary values
  __shared__ float redB[16], redC[16];

  // ---- params phase (waves 0..7: unit = type*4+head)
  if (w < 8) {
    const int type = w >> 2, head = w & 3;
    const float* pp = P + (size_t)b * 1072 + (type == 0 ? head * 70 : 280 + head * 198);
    const float kv = tanhf(pp[l]);
    float ss = kv * kv;
#pragma unroll
    for (int off = 32; off > 0; off >>= 1) ss += __shfl_xor(ss, off);
    knbs[w * 64 + l] = (unsigned short)f2bf(kv * rsq_(fmaxf(ss, 1e-20f)));
    if (l == 0) {
      parb[w][0] = softplusf_(pp[64]);
      parb[w][1] = sigmoidf_(pp[65]);
      const float s0 = pp[66], s1 = pp[67], s2 = pp[68];
      const float mx = fmaxf(s0, fmaxf(s1, s2));
      const float e0 = expf(s0 - mx), e1 = expf(s1 - mx), e2 = expf(s2 - mx);
      const float inv = 1.f / (e0 + e1 + e2);
      parb[w][2] = e0 * inv; parb[w][3] = e1 * inv; parb[w][4] = e2 * inv;
      parb[w][5] = 1.f + softplusf_(pp[69]);
    }
    if (type == 1 && l < 32) {
      ebp[head][l] = cvtpk(sigmoidf_(pp[70 + 2 * l]), sigmoidf_(pp[70 + 2 * l + 1]));
      abp[head][l] = cvtpk(tanhf(pp[134 + 2 * l]), tanhf(pp[134 + 2 * l + 1]));
    }
  }

  // ---- staging: f32 memory -> bf16 LDS image (swizzled 16B chunks)
  {
    const float4* src = (const float4*)(mem0 + (size_t)b * 65536);
#pragma unroll 4
    for (int k = 0; k < 16; ++k) {
      const int v = k * 1024 + t;          // float4 index; n = v>>4, ch = v&15
      const float4 f = src[v];
      const int n = v >> 4, ch = v & 15;
      uint2 pk;
      pk.x = cvtpk(f.x, f.y);
      pk.y = cvtpk(f.z, f.w);
      *(uint2*)((char*)smem + n * 128 + (((ch >> 1) ^ (n & 7)) << 4) + ((ch & 1) << 3)) = pk;
    }
  }
  __syncthreads();  // image + params visible

  // ---- key B-fragments from LDS (cols 0..3 read keys, 4..7 write keys)
  bf16x8 kb0 = {}, kb1 = {};
  if (p < 8) {
    kb0 = *(const bf16x8*)&knbs[p * 64 + q * 8];
    kb1 = *(const bf16x8*)&knbs[p * 64 + 32 + q * 8];
  }

  // ---- MFMA score pass over wave-owned rows: scores for head hj + Gram norms
  auto score_pass = [&](int hj) {
#pragma unroll
    for (int tt = 0; tt < 4; ++tt) {
      const int tile = w * 4 + tt;
      const int row = tile * 16 + p;
      const bf16x8 a0 = *(const bf16x8*)((char*)smem + row * 128 + (((q) ^ (row & 7)) << 4));
      const bf16x8 a1 = *(const bf16x8*)((char*)smem + row * 128 + (((q + 4) ^ (row & 7)) << 4));
      f32x4 sacc = {0.f, 0.f, 0.f, 0.f}, gacc = {0.f, 0.f, 0.f, 0.f};
      sacc = __builtin_amdgcn_mfma_f32_16x16x32_bf16(a0, kb0, sacc, 0, 0, 0);
      sacc = __builtin_amdgcn_mfma_f32_16x16x32_bf16(a1, kb1, sacc, 0, 0, 0);
      gacc = __builtin_amdgcn_mfma_f32_16x16x32_bf16(a0, a0, gacc, 0, 0, 0);
      gacc = __builtin_amdgcn_mfma_f32_16x16x32_bf16(a1, a1, gacc, 0, 0, 0);
      if (p == hj)       *(f32x4*)&Ar[tile * 16 + q * 4] = sacc;
      if (p == 4 + hj)   *(f32x4*)&Aw[tile * 16 + q * 4] = sacc;
      if ((p >> 2) == q) nrm_s[tile * 16 + p] = gacc[p & 3];
    }
  };

  score_pass(0);
  __syncthreads();  // head-0 scores + norms visible

  const int h = t >> 9;      // 0: read half (waves 0-7), 1: write half (8-15)
  const int th = t & 511;
  const int w8 = (t & 511) >> 6;   // chunk index within half (0..7)
  float* Abuf = h ? Aw : Ar;
  float* Wbuf = h ? wpW : wpR;

  for (int i = 0; i < 4; ++i) {
    const float beta = parb[h * 4 + i][0], g = parb[h * 4 + i][1];
    const float sh0 = parb[h * 4 + i][2], sh1 = parb[h * 4 + i][3], sh2 = parb[h * 4 + i][4];
    const float gamma = parb[h * 4 + i][5];
    const float* prevw = (h ? prev_w_w : prev_w_r) + ((size_t)i * 512 + b) * 1024;

    // ---- P1: prevw -> regs (+ boundary table) + unscaled exp of scores
    const float pv0 = prevw[th];
    const float pv1 = prevw[th + 512];
    float e2_[2];
    float s = 0.f;
#pragma unroll
    for (int k = 0; k < 2; ++k) {
      const int u = th + 512 * k;
      const float z = beta * Abuf[u] * rsq_(fmaxf(nrm_s[u], 1e-20f));
      e2_[k] = __expf(z);
      s += e2_[k];
    }
    Abuf[th] = e2_[0];
    Abuf[th + 512] = e2_[1];
    if (l == 0)  { pb[h][w8][0] = pv0; pb[h][w8 + 8][0] = pv1; }
    if (l == 63) { pb[h][w8][1] = pv0; pb[h][w8 + 8][1] = pv1; }
#pragma unroll
    for (int off = 32; off > 0; off >>= 1) s += __shfl_xor(s, off);
    if (l == 0) redB[w] = s;
    __syncthreads();  // S1

    // ---- P2: gate + shift + sharpen; neighbors via shfl, boundaries via pb
    float gsum = 0.f;
#pragma unroll
    for (int j = 0; j < 8; ++j) gsum += redB[h * 8 + j];
    const float gi = g / gsum;
    const float gm = 1.f - g;
    float s2 = 0.f;
#pragma unroll
    for (int k = 0; k < 2; ++k) {
      const int u = th + 512 * k;
      const float wg0 = gi * Abuf[u] + gm * ((k == 0) ? pv0 : pv1);
      float wgm = __shfl_up(wg0, 1);
      float wgp = __shfl_down(wg0, 1);
      if (l == 0) {
        const int um = (u + 1023) & 1023;
        wgm = gi * Abuf[um] + gm * pb[h][um >> 6][1];
      }
      if (l == 63) {
        const int up = (u + 1) & 1023;
        wgp = gi * Abuf[up] + gm * pb[h][up >> 6][0];
      }
      const float ws = sh0 * wgm + sh1 * wg0 + sh2 * wgp;
      const float wp = (ws > 0.f) ? exp2f(gamma * __log2f(ws)) : 0.f;
      Wbuf[u] = wp;
      s2 += wp;
    }
#pragma unroll
    for (int off = 32; off > 0; off >>= 1) s2 += __shfl_xor(s2, off);
    if (l == 0) redC[w] = s2;
    __syncthreads();  // S2

    // ---- P3: sweep wave-owned rows (reads + in-place update, read-side norm)
    float ir = 0.f, iw = 0.f;
#pragma unroll
    for (int j = 0; j < 8; ++j) { ir += redC[j]; iw += redC[8 + j]; }
    const float inv2r = 1.f / (ir + EPS_);
    const float inv2w = 1.f / (iw + EPS_);

    float e_0 = 0.f, e_1 = 0.f, e_2 = 0.f, e_3 = 0.f;
    float a_0 = 0.f, a_1 = 0.f, a_2 = 0.f, a_3 = 0.f;
    if (i < 3) {
      const unsigned ue0 = ebp[i][p * 2], ue1 = ebp[i][p * 2 + 1];
      const unsigned ua0 = abp[i][p * 2], ua1 = abp[i][p * 2 + 1];
      e_0 = bflo2f(ue0); e_1 = bfhi2f(ue0); e_2 = bflo2f(ue1); e_3 = bfhi2f(ue1);
      a_0 = bflo2f(ua0); a_1 = bfhi2f(ua0); a_2 = bflo2f(ua1); a_3 = bfhi2f(ua1);
    }

    // two hoisted swizzled base pointers: rows w*64+{q, 4+q} (+8 per step)
    char* const base0 = (char*)smem + (w * 64 + q) * 128 + ((((p >> 1) ^ q) << 4) | ((p & 1) << 3));
    char* const base1 = (char*)smem + (w * 64 + 4 + q) * 128 + ((((p >> 1) ^ (4 + q)) << 4) | ((p & 1) << 3));
    float r[4] = {0.f, 0.f, 0.f, 0.f};
#pragma unroll 2
    for (int it2 = 0; it2 < 8; ++it2) {
      {
        const int row = w * 64 + it2 * 8 + q;
        char* addr = base0 + it2 * 1024;
        uint2 pk = *(uint2*)addr;
        const float v0 = bflo2f(pk.x), v1 = bfhi2f(pk.x);
        const float v2 = bflo2f(pk.y), v3 = bfhi2f(pk.y);
        const float wr = wpR[row] * inv2r;
        r[0] = fmaf(wr, v0, r[0]); r[1] = fmaf(wr, v1, r[1]);
        r[2] = fmaf(wr, v2, r[2]); r[3] = fmaf(wr, v3, r[3]);
        if (i < 3) {
          const float ww = wpW[row] * inv2w;
          pk.x = cvtpk(fmaf(v0, fmaf(-ww, e_0, 1.f), ww * a_0),
                       fmaf(v1, fmaf(-ww, e_1, 1.f), ww * a_1));
          pk.y = cvtpk(fmaf(v2, fmaf(-ww, e_2, 1.f), ww * a_2),
                       fmaf(v3, fmaf(-ww, e_3, 1.f), ww * a_3));
          *(uint2*)addr = pk;
        }
      }
      {
        const int row = w * 64 + it2 * 8 + 4 + q;
        char* addr = base1 + it2 * 1024;
        uint2 pk = *(uint2*)addr;
        const float v0 = bflo2f(pk.x), v1 = bfhi2f(pk.x);
        const float v2 = bflo2f(pk.y), v3 = bfhi2f(pk.y);
        const float wr = wpR[row] * inv2r;
        r[0] = fmaf(wr, v0, r[0]); r[1] = fmaf(wr, v1, r[1]);
        r[2] = fmaf(wr, v2, r[2]); r[3] = fmaf(wr, v3, r[3]);
        if (i < 3) {
          const float ww = wpW[row] * inv2w;
          pk.x = cvtpk(fmaf(v0, fmaf(-ww, e_0, 1.f), ww * a_0),
                       fmaf(v1, fmaf(-ww, e_1, 1.f), ww * a_1));
          pk.y = cvtpk(fmaf(v2, fmaf(-ww, e_2, 1.f), ww * a_2),
                       fmaf(v3, fmaf(-ww, e_3, 1.f), ww * a_3));
          *(uint2*)addr = pk;
        }
      }
    }
    // fold read partials over the 4 q-groups (lane bits 4,5)
#pragma unroll
    for (int c = 0; c < 4; ++c) {
      r[c] += __shfl_xor(r[c], 16);
      r[c] += __shfl_xor(r[c], 32);
    }
    if (q == 0) *(f32x4*)&racc[w][p * 4] = *(f32x4*)r;

    if (i < 3) score_pass(i + 1);  // own-row scores/norms from updated image
    __syncthreads();               // S3

    if (t < 64) {
      float s3 = 0.f;
#pragma unroll
      for (int wv = 0; wv < 16; ++wv) s3 += racc[wv][t];
      Aoutb[(size_t)b * 768 + 512 + i * 64 + t] = (unsigned short)f2bf(s3);
    }
  }
}

extern "C" void kernel_launch(void* const* d_in, const int* in_sizes, int n_in,
                              void* d_out, int out_size, void* d_ws, size_t ws_size,
                              hipStream_t stream) {
  (void)in_sizes; (void)n_in; (void)out_size; (void)ws_size;
  const float* in_data = (const float*)d_in[0];
  const float* memory = (const float*)d_in[1];
  const float* prev_reads = (const float*)d_in[2];
  const float* prev_w_r = (const float*)d_in[3];
  const float* prev_w_w = (const float*)d_in[4];
  const float* h0 = (const float*)d_in[5];
  const float* c0 = (const float*)d_in[6];
  const float* W_ih = (const float*)d_in[7];
  const float* b_ih = (const float*)d_in[8];
  const float* W_hh = (const float*)d_in[9];
  const float* b_hh = (const float*)d_in[10];
  const float* W_rh = (const float*)d_in[11];
  const float* b_rh = (const float*)d_in[12];
  const float* W_wh = (const float*)d_in[13];
  const float* b_wh = (const float*)d_in[14];
  const float* W_out = (const float*)d_in[15];
  const float* b_out = (const float*)d_in[16];
  float* out = (float*)d_out;

  char* base = (char*)d_ws;
  auto alloc = [&](size_t bytes) -> char* {
    char* p = base; base += (bytes + 255) & ~(size_t)255; return p;
  };
  unsigned short* x2b   = (unsigned short*)alloc((size_t)512 * 1024 * 2);
  unsigned short* Wcatb = (unsigned short*)alloc((size_t)2048 * 1024 * 2);
  float* bcat           = (float*)alloc(2048 * 4);
  float* gates          = (float*)alloc((size_t)512 * 2048 * 4);
  unsigned short* W2b   = (unsigned short*)alloc((size_t)1072 * 512 * 2);
  float* bcat2          = (float*)alloc(1072 * 4);
  unsigned short* Woutb = (unsigned short*)alloc((size_t)256 * 768 * 2);
  float* P              = (float*)alloc((size_t)512 * 1072 * 4);
  unsigned short* Aoutb = (unsigned short*)alloc((size_t)512 * 768 * 2);

  k_prep<<<2048, 256, 0, stream>>>(in_data, prev_reads, h0, W_ih, W_hh, b_ih, b_hh,
                                   W_rh, W_wh, W_out, b_rh, b_wh,
                                   x2b, Wcatb, bcat, W2b, Woutb, bcat2);
  k_gemm_mfma<false><<<dim3(64, 16), 64, 0, stream>>>(x2b, 1024, Wcatb, bcat, gates, 2048, 1024, 2048);
  k_lstm<<<1024, 256, 0, stream>>>(gates, c0, Aoutb);
  k_gemm_mfma<false><<<dim3(34, 16), 64, 0, stream>>>(Aoutb, 768, W2b, bcat2, P, 1072, 512, 1072);
  k_mega<<<512, 1024, 0, stream>>>(memory, P, prev_w_r, prev_w_w, Aoutb);
  k_gemm_mfma<true><<<dim3(8, 16), 64, 0, stream>>>(Aoutb, 768, Woutb, b_out, out, 256, 768, 256);
}